// Round 9
// baseline (73.779 us; speedup 1.0000x reference)
//
#include <hip/hip_runtime.h>

#define L_SEQ 32768
#define NDIM 256
#define HDIM 256
#define NCAT 512   // 2*NDIM (re/im interleaved)
#define LC 64      // scan chunk length
#define NCHUNK 512 // L_SEQ / LC

typedef unsigned short u16;
typedef unsigned int u32;
typedef __bf16 bf16x8 __attribute__((ext_vector_type(8)));
typedef float f32x4 __attribute__((ext_vector_type(4)));
typedef __attribute__((address_space(3))) void lds_void;
typedef const __attribute__((address_space(1))) void gbl_void;

__device__ __forceinline__ u16 f2bf(float f) {
  u32 u = __builtin_bit_cast(u32, f);
  u = u + 0x7fffu + ((u >> 16) & 1u);
  return (u16)(u >> 16);
}
__device__ __forceinline__ float bf2f(u16 v) {
  u32 u = ((u32)v) << 16;
  return __builtin_bit_cast(float, u);
}

// ---------------------------------------------------------------------------
// PREP: x -> bf16, build Bcat (512x256 bf16), Ccat (256x512 bf16), lambda tables
// ---------------------------------------------------------------------------
__global__ __launch_bounds__(256) void prep_kernel(
    const float* __restrict__ x,
    const float* __restrict__ nu_log, const float* __restrict__ theta_log,
    const float* __restrict__ B_re, const float* __restrict__ B_im,
    const float* __restrict__ C_re, const float* __restrict__ C_im,
    const float* __restrict__ gamma_log,
    u16* __restrict__ x_bf, u16* __restrict__ Bcat, u16* __restrict__ Ccat,
    float2* __restrict__ lam, float2* __restrict__ lam64)
{
  const int blk = blockIdx.x, tid = threadIdx.x;
  if (blk < 2048) {
    const float4* src = ((const float4*)x) + (size_t)blk * 1024;
    ushort4* dst = ((ushort4*)x_bf) + (size_t)blk * 1024;
#pragma unroll
    for (int j = 0; j < 4; ++j) {
      float4 v = src[j * 256 + tid];
      dst[j * 256 + tid] = make_ushort4(f2bf(v.x), f2bf(v.y), f2bf(v.z), f2bf(v.w));
    }
  } else if (blk < 2560) {
    int b2 = blk - 2048;
    int jj = b2 >> 1, p = b2 & 1;
    float g = expf(gamma_log[jj]);
    const float* src = (p ? B_im : B_re) + (size_t)jj * HDIM;
    Bcat[(size_t)b2 * HDIM + tid] = f2bf(src[tid] * g);
  } else if (blk < 2816) {
    int h = blk - 2560;
#pragma unroll
    for (int half = 0; half < 2; ++half) {
      int nc = half * 256 + tid;
      int jj = nc >> 1, p = nc & 1;
      float v = p ? -C_im[(size_t)h * NDIM + jj] : C_re[(size_t)h * NDIM + jj];
      Ccat[(size_t)h * NCAT + nc] = f2bf(v);
    }
  } else {
    float nu_e = expf(nu_log[tid]);
    float th = expf(theta_log[tid]);
    float r = expf(-nu_e);
    lam[tid] = make_float2(r * cosf(th), r * sinf(th));
    float r64 = expf(-(float)LC * nu_e);
    float ph = (float)LC * th;
    lam64[tid] = make_float2(r64 * cosf(ph), r64 * sinf(ph));
  }
}

// ---------------------------------------------------------------------------
// GEMM1 (verified): Bu[m][n] = sum_k A[m][k]*Bm[n][k], bf16 out.
// ---------------------------------------------------------------------------
__global__ __launch_bounds__(256) void gemm1_kernel(
    const u16* __restrict__ A,   // M x K bf16
    const u16* __restrict__ Bm,  // N x K bf16
    u16* __restrict__ Cout,      // M x N bf16
    int M, int N, int K)
{
  constexpr int BM = 128, BN = 128, BK = 32;
  __shared__ u16 lA[BM * BK];
  __shared__ u16 lB[BN * BK];
  const int tid = threadIdx.x;
  const int lane = tid & 63, wave = tid >> 6;
  const int bn = blockIdx.x, bm = blockIdx.y;
  const int row0 = bm * BM, col0 = bn * BN;
  const int wm = (wave >> 1) * 64, wn = (wave & 1) * 64;
  const int fr = lane & 15, fo = (lane >> 4) * 8;

  f32x4 acc[4][4] = {};
  const int nkt = K / BK;
  for (int kt = 0; kt < nkt; ++kt) {
    const int k0 = kt * BK;
#pragma unroll
    for (int j = 0; j < 2; ++j) {
      int chunk = j * 256 + tid;
      int r = chunk >> 2, c = chunk & 3;
      const u16* ga = A + (size_t)(row0 + r) * K + (k0 + c * 8);
      const u16* gb = Bm + (size_t)(col0 + r) * K + (k0 + c * 8);
      __builtin_amdgcn_global_load_lds((gbl_void*)ga, (lds_void*)&lA[chunk * 8], 16, 0, 0);
      __builtin_amdgcn_global_load_lds((gbl_void*)gb, (lds_void*)&lB[chunk * 8], 16, 0, 0);
    }
    __syncthreads();

    bf16x8 af[4], bfr[4];
#pragma unroll
    for (int i = 0; i < 4; ++i) {
      af[i]  = *reinterpret_cast<const bf16x8*>(&lA[(wm + i * 16 + fr) * BK + fo]);
      bfr[i] = *reinterpret_cast<const bf16x8*>(&lB[(wn + i * 16 + fr) * BK + fo]);
    }
#pragma unroll
    for (int i = 0; i < 4; ++i)
#pragma unroll
      for (int j = 0; j < 4; ++j)
        acc[i][j] = __builtin_amdgcn_mfma_f32_16x16x32_bf16(af[i], bfr[j], acc[i][j], 0, 0, 0);
    __syncthreads();
  }

  const int fq = lane >> 4;
#pragma unroll
  for (int i = 0; i < 4; ++i)
#pragma unroll
    for (int j = 0; j < 4; ++j) {
      int cg = col0 + wn + j * 16 + fr;
#pragma unroll
      for (int r = 0; r < 4; ++r) {
        int rg = row0 + wm + i * 16 + fq * 4 + r;
        Cout[(size_t)rg * N + cg] = f2bf(acc[i][j][r]);
      }
    }
}

// ---------------------------------------------------------------------------
// Scan phase 1 (verified): per-chunk final state over bf16 Bu
// ---------------------------------------------------------------------------
__global__ __launch_bounds__(256) void scan_carry_kernel(
    const ushort2* __restrict__ Bu2, const float2* __restrict__ lam,
    float2* __restrict__ carry)
{
  const int n = threadIdx.x, b = blockIdx.x;
  const float2 la = lam[n];
  float sre = 0.f, sim = 0.f;
  const ushort2* p = Bu2 + (size_t)b * LC * NDIM + n;
#pragma unroll 8
  for (int j = 0; j < LC; ++j) {
    ushort2 bu = p[(size_t)j * NDIM];
    float bre = bf2f(bu.x), bim = bf2f(bu.y);
    float nre = la.x * sre - la.y * sim + bre;
    float nim = la.x * sim + la.y * sre + bim;
    sre = nre; sim = nim;
  }
  carry[(size_t)b * NDIM + n] = make_float2(sre, sim);
}

// ---------------------------------------------------------------------------
// Scan phase 2 (verified): log-depth Hillis-Steele in LDS.
// ---------------------------------------------------------------------------
__global__ __launch_bounds__(512) void carry_scan_kernel(
    const float2* __restrict__ carry, const float2* __restrict__ lam64,
    float2* __restrict__ corr)
{
  __shared__ float4 e[NCHUNK];
  const int n = blockIdx.x;
  const int b = threadIdx.x;
  float2 a = lam64[n];
  float2 v = carry[(size_t)b * NDIM + n];
  e[b] = make_float4(a.x, a.y, v.x, v.y);
  __syncthreads();
#pragma unroll
  for (int d = 1; d < NCHUNK; d <<= 1) {
    float4 prev;
    if (b >= d) prev = e[b - d];
    __syncthreads();
    if (b >= d) {
      float2 ap = make_float2(prev.x, prev.y), vp = make_float2(prev.z, prev.w);
      float2 na, nv;
      na.x = a.x * ap.x - a.y * ap.y;
      na.y = a.x * ap.y + a.y * ap.x;
      nv.x = a.x * vp.x - a.y * vp.y + v.x;
      nv.y = a.x * vp.y + a.y * vp.x + v.y;
      a = na; v = nv;
      e[b] = make_float4(a.x, a.y, v.x, v.y);
    }
    __syncthreads();
  }
  if (b == 0) corr[n] = make_float2(0.f, 0.f);
  if (b < NCHUNK - 1) corr[(size_t)(b + 1) * NDIM + n] = v;
}

// ---------------------------------------------------------------------------
// GEMM2 fused: one block = one chunk (64 rows) x 256 out-cols, 256 thr /
// 4 waves. Each wave owns 64x64 (acc 4x4, 16 MFMA per k-step) -- gemm1's
// proven inner shape. Stage Bu + Ccat kt=0 -> in-place scan -> reg-prefetch
// pipelined k-loop (R8-verified pattern) -> +x*D epilogue. LDS 80KB.
// ---------------------------------------------------------------------------
__global__ __launch_bounds__(256, 2) void gemm2_kernel(
    const u16* __restrict__ Bu,   // L x 512 bf16
    const u16* __restrict__ Cc,   // 256 x 512 bf16
    const float2* __restrict__ lam,
    const float2* __restrict__ corr,
    const u16* __restrict__ xbf,  // L x 256 bf16
    const float* __restrict__ Dv,
    float* __restrict__ out)      // L x 256 f32
{
  constexpr int BM = 64, BK = 32, K = NCAT; // 16 k-steps
  __shared__ u16 sT[BM * K];      // 64KB: Bu tile -> (swizzled) s tile
  __shared__ u16 lB1[256 * BK];   // 16KB Ccat slice (reg-prefetch pipelined)
  const int tid = threadIdx.x;
  const int lane = tid & 63, wave = tid >> 6;
  const int bm = blockIdx.x;
  const int row0 = bm * BM;
  const int wn = wave * 64;       // wave's 64-col strip; rows: all 64
  const int fr = lane & 15, fq = lane >> 4;
  char* sb = (char*)sT;

  // stage Bu tile linear (4096 x 16B) + Ccat slice kt=0 (1024 x 16B)
#pragma unroll
  for (int j = 0; j < 16; ++j) {
    int q = j * 256 + tid;
    int row = q >> 6, off = q & 63;
    const u16* g = Bu + (size_t)(row0 + row) * NCAT + off * 8;
    __builtin_amdgcn_global_load_lds((gbl_void*)g, (lds_void*)&sT[q * 8], 16, 0, 0);
  }
#pragma unroll
  for (int j = 0; j < 4; ++j) {
    int q = j * 256 + tid;
    int row = q >> 2, c = q & 3;
    const u16* g = Cc + (size_t)row * K + c * 8;
    __builtin_amdgcn_global_load_lds((gbl_void*)g, (lds_void*)&lB1[q * 8], 16, 0, 0);
  }
  float2 la = lam[tid];
  float2 c0 = corr[(size_t)bm * NDIM + tid];
  __syncthreads();

  // in-place scan (each thread owns complex channel tid; reads linear,
  // writes swizzled: byte ^= (row&7)<<4; write of row R depends on this
  // wave's earlier read of row R -> wave-ordered DS keeps it race-free)
  {
    float sre = c0.x, sim = c0.y;
    ushort2 buf[8], nbuf[8];
    const int lb = tid * 4;
#pragma unroll
    for (int s = 0; s < 8; ++s) buf[s] = *(const ushort2*)(sb + s * 1024 + lb);
#pragma unroll
    for (int b8 = 0; b8 < 8; ++b8) {
      if (b8 < 7) {
#pragma unroll
        for (int s = 0; s < 8; ++s)
          nbuf[s] = *(const ushort2*)(sb + (b8 * 8 + 8 + s) * 1024 + lb);
      }
#pragma unroll
      for (int s = 0; s < 8; ++s) {
        int row = b8 * 8 + s;
        float bre = bf2f(buf[s].x), bim = bf2f(buf[s].y);
        float nre = la.x * sre - la.y * sim + bre;
        float nim = la.x * sim + la.y * sre + bim;
        sre = nre; sim = nim;
        *(ushort2*)(sb + row * 1024 + (lb ^ ((row & 7) << 4))) =
            make_ushort2(f2bf(sre), f2bf(sim));
      }
#pragma unroll
      for (int s = 0; s < 8; ++s) buf[s] = nbuf[s];
    }
  }
  __syncthreads();

  // MFMA: 16 k-steps, reg-prefetch pipeline (R8-verified):
  //   ds_read frags -> regs; barrier; issue stage kt+1 into lB1;
  //   MFMA from regs (loads in flight); barrier.
  f32x4 acc[4][4] = {};
#pragma unroll 1
  for (int kt = 0; kt < 16; ++kt) {
    bf16x8 af[4], bfr[4];
#pragma unroll
    for (int j = 0; j < 4; ++j)
      bfr[j] = *(const bf16x8*)(&lB1[(wn + j * 16 + fr) * BK + fq * 8]);
#pragma unroll
    for (int i = 0; i < 4; ++i) {
      int row = i * 16 + fr;
      int wb = kt * 64 + fq * 16;
      af[i] = *(const bf16x8*)(sb + row * 1024 + (wb ^ ((row & 7) << 4)));
    }
    __syncthreads();
    __builtin_amdgcn_sched_barrier(0);
    if (kt < 15) {
#pragma unroll
      for (int j = 0; j < 4; ++j) {
        int q = j * 256 + tid;
        int row = q >> 2, c = q & 3;
        const u16* g = Cc + (size_t)row * K + (kt + 1) * BK + c * 8;
        __builtin_amdgcn_global_load_lds((gbl_void*)g, (lds_void*)&lB1[q * 8], 16, 0, 0);
      }
    }
    __builtin_amdgcn_sched_barrier(0);
#pragma unroll
    for (int i = 0; i < 4; ++i)
#pragma unroll
      for (int j = 0; j < 4; ++j)
        acc[i][j] = __builtin_amdgcn_mfma_f32_16x16x32_bf16(af[i], bfr[j], acc[i][j], 0, 0, 0);
    __syncthreads();
  }

  // epilogue: y = acc + x*D
#pragma unroll
  for (int i = 0; i < 4; ++i)
#pragma unroll
    for (int j = 0; j < 4; ++j) {
      int cg = wn + j * 16 + fr;
      float dvc = Dv[cg];
#pragma unroll
      for (int r = 0; r < 4; ++r) {
        int rg = row0 + i * 16 + fq * 4 + r;
        float v = acc[i][j][r] + bf2f(xbf[(size_t)rg * HDIM + cg]) * dvc;
        out[(size_t)rg * HDIM + cg] = v;
      }
    }
}

// ---------------------------------------------------------------------------
extern "C" void kernel_launch(void* const* d_in, const int* in_sizes, int n_in,
                              void* d_out, int out_size, void* d_ws, size_t ws_size,
                              hipStream_t stream)
{
  (void)in_sizes; (void)n_in; (void)out_size; (void)ws_size;
  const float* x         = (const float*)d_in[0];
  const float* nu_log    = (const float*)d_in[1];
  const float* theta_log = (const float*)d_in[2];
  const float* B_re      = (const float*)d_in[3];
  const float* B_im      = (const float*)d_in[4];
  const float* C_re      = (const float*)d_in[5];
  const float* C_im      = (const float*)d_in[6];
  const float* Dv        = (const float*)d_in[7];
  const float* gamma_log = (const float*)d_in[8];

  char* ws = (char*)d_ws;
  u16*    x_bf  = (u16*)ws;                                  // 16 MB
  u16*    Bu_bf = (u16*)(ws + ((size_t)16 << 20));           // 32 MB
  u16*    Bcat  = (u16*)(ws + ((size_t)48 << 20));           // 256 KB
  u16*    Ccat  = (u16*)(ws + ((size_t)48 << 20) + 262144);  // 256 KB
  float2* lam   = (float2*)(ws + ((size_t)48 << 20) + 524288);
  float2* lam64 = (float2*)(ws + ((size_t)48 << 20) + 524288 + 4096);
  float2* carry = (float2*)(ws + ((size_t)49 << 20));        // 1 MB
  float2* corr  = (float2*)(ws + ((size_t)50 << 20));        // 1 MB

  prep_kernel<<<2817, 256, 0, stream>>>(x, nu_log, theta_log, B_re, B_im,
                                        C_re, C_im, gamma_log,
                                        x_bf, Bcat, Ccat, lam, lam64);

  gemm1_kernel<<<dim3(NCAT / 128, L_SEQ / 128), 256, 0, stream>>>(
      x_bf, Bcat, Bu_bf, L_SEQ, NCAT, HDIM);

  scan_carry_kernel<<<NCHUNK, 256, 0, stream>>>((const ushort2*)Bu_bf, lam, carry);

  carry_scan_kernel<<<NDIM, 512, 0, stream>>>(carry, lam64, corr);

  gemm2_kernel<<<NCHUNK, 256, 0, stream>>>(
      Bu_bf, Ccat, lam, corr, x_bf, Dv, (float*)d_out);
}

// Round 10
// 73.763 us; speedup vs baseline: 1.0002x; 1.0002x over previous
//
#include <hip/hip_runtime.h>

#define L_SEQ 32768
#define NDIM 256
#define HDIM 256
#define NCAT 512   // 2*NDIM (re/im interleaved)
#define LC 64      // scan chunk length
#define NCHUNK 512 // L_SEQ / LC

typedef unsigned short u16;
typedef unsigned int u32;
typedef __bf16 bf16x8 __attribute__((ext_vector_type(8)));
typedef float f32x4 __attribute__((ext_vector_type(4)));
typedef __attribute__((address_space(3))) void lds_void;
typedef const __attribute__((address_space(1))) void gbl_void;

__device__ __forceinline__ u16 f2bf(float f) {
  u32 u = __builtin_bit_cast(u32, f);
  u = u + 0x7fffu + ((u >> 16) & 1u);
  return (u16)(u >> 16);
}
__device__ __forceinline__ float bf2f(u16 v) {
  u32 u = ((u32)v) << 16;
  return __builtin_bit_cast(float, u);
}

// ---------------------------------------------------------------------------
// PREP: x -> bf16, build PRE-SWIZZLED Bcat (512x256) / Ccat (256x512), lambda.
// Swizzle: linear [row][64B] staging + read byte ^= ((row&7)<<4) must yield
// original element; physical slot (pr,pc) holds logical (lr = pr^((pr>>2)&1),
// fq = pc^(lr&3)) -- bijective, verified.
// ---------------------------------------------------------------------------
__global__ __launch_bounds__(256) void prep_kernel(
    const float* __restrict__ x,
    const float* __restrict__ nu_log, const float* __restrict__ theta_log,
    const float* __restrict__ B_re, const float* __restrict__ B_im,
    const float* __restrict__ C_re, const float* __restrict__ C_im,
    const float* __restrict__ gamma_log,
    u16* __restrict__ x_bf, u16* __restrict__ Bcat, u16* __restrict__ Ccat,
    float2* __restrict__ lam, float2* __restrict__ lam64)
{
  const int blk = blockIdx.x, tid = threadIdx.x;
  if (blk < 2048) {
    const float4* src = ((const float4*)x) + (size_t)blk * 1024;
    ushort4* dst = ((ushort4*)x_bf) + (size_t)blk * 1024;
#pragma unroll
    for (int j = 0; j < 4; ++j) {
      float4 v = src[j * 256 + tid];
      dst[j * 256 + tid] = make_ushort4(f2bf(v.x), f2bf(v.y), f2bf(v.z), f2bf(v.w));
    }
  } else if (blk < 2560) {
    // Bcat physical row pr; content from logical row lr, permuted col
    int pr = blk - 2048;
    int lr = pr ^ ((pr >> 2) & 1);
    int jj = lr >> 1, p = lr & 1;
    float g = expf(gamma_log[jj]);
    const float* src = (p ? B_im : B_re) + (size_t)jj * HDIM;
    int kt = tid >> 5, w = tid & 31, pc = w >> 3, e = w & 7;
    int lc = kt * 32 + (pc ^ (lr & 3)) * 8 + e;
    Bcat[(size_t)pr * HDIM + tid] = f2bf(src[lc] * g);
  } else if (blk < 2816) {
    // Ccat physical row ph; content from logical row lr, permuted col
    int ph = blk - 2560;
    int lr = ph ^ ((ph >> 2) & 1);
#pragma unroll
    for (int half = 0; half < 2; ++half) {
      int pcol = half * 256 + tid;
      int kt = pcol >> 5, w = pcol & 31, pc = w >> 3, e = w & 7;
      int lc2 = kt * 32 + (pc ^ (lr & 3)) * 8 + e;
      int jj = lc2 >> 1, p = lc2 & 1;
      float v = p ? -C_im[(size_t)lr * NDIM + jj] : C_re[(size_t)lr * NDIM + jj];
      Ccat[(size_t)ph * NCAT + pcol] = f2bf(v);
    }
  } else {
    float nu_e = expf(nu_log[tid]);
    float th = expf(theta_log[tid]);
    float r = expf(-nu_e);
    lam[tid] = make_float2(r * cosf(th), r * sinf(th));
    float r64 = expf(-(float)LC * nu_e);
    float ph = (float)LC * th;
    lam64[tid] = make_float2(r64 * cosf(ph), r64 * sinf(ph));
  }
}

// ---------------------------------------------------------------------------
// GEMM1 (verified loop): Bu[m][n] = sum_k A[m][k]*Bm[n][k], bf16 out.
// Bm is pre-swizzled -> bfr reads bank-conflict-free via XOR.
// ---------------------------------------------------------------------------
__global__ __launch_bounds__(256) void gemm1_kernel(
    const u16* __restrict__ A,   // M x K bf16
    const u16* __restrict__ Bm,  // N x K bf16 (pre-swizzled)
    u16* __restrict__ Cout,      // M x N bf16
    int M, int N, int K)
{
  constexpr int BM = 128, BN = 128, BK = 32;
  __shared__ u16 lA[BM * BK];
  __shared__ u16 lB[BN * BK];
  const int tid = threadIdx.x;
  const int lane = tid & 63, wave = tid >> 6;
  const int bn = blockIdx.x, bm = blockIdx.y;
  const int row0 = bm * BM, col0 = bn * BN;
  const int wm = (wave >> 1) * 64, wn = (wave & 1) * 64;
  const int fr = lane & 15, fq = lane >> 4, fo = fq * 8;
  const char* lbB = (const char*)lB;

  f32x4 acc[4][4] = {};
  const int nkt = K / BK;
  for (int kt = 0; kt < nkt; ++kt) {
    const int k0 = kt * BK;
#pragma unroll
    for (int j = 0; j < 2; ++j) {
      int chunk = j * 256 + tid;
      int r = chunk >> 2, c = chunk & 3;
      const u16* ga = A + (size_t)(row0 + r) * K + (k0 + c * 8);
      const u16* gb = Bm + (size_t)(col0 + r) * K + (k0 + c * 8);
      __builtin_amdgcn_global_load_lds((gbl_void*)ga, (lds_void*)&lA[chunk * 8], 16, 0, 0);
      __builtin_amdgcn_global_load_lds((gbl_void*)gb, (lds_void*)&lB[chunk * 8], 16, 0, 0);
    }
    __syncthreads();

    bf16x8 af[4], bfr[4];
#pragma unroll
    for (int i = 0; i < 4; ++i) {
      af[i] = *reinterpret_cast<const bf16x8*>(&lA[(wm + i * 16 + fr) * BK + fo]);
      int rowb = wn + i * 16 + fr;
      bfr[i] = *(const bf16x8*)(lbB + ((rowb * 64 + fq * 16) ^ ((rowb & 7) << 4)));
    }
#pragma unroll
    for (int i = 0; i < 4; ++i)
#pragma unroll
      for (int j = 0; j < 4; ++j)
        acc[i][j] = __builtin_amdgcn_mfma_f32_16x16x32_bf16(af[i], bfr[j], acc[i][j], 0, 0, 0);
    __syncthreads();
  }

#pragma unroll
  for (int i = 0; i < 4; ++i)
#pragma unroll
    for (int j = 0; j < 4; ++j) {
      int cg = col0 + wn + j * 16 + fr;
#pragma unroll
      for (int r = 0; r < 4; ++r) {
        int rg = row0 + wm + i * 16 + fq * 4 + r;
        Cout[(size_t)rg * N + cg] = f2bf(acc[i][j][r]);
      }
    }
}

// ---------------------------------------------------------------------------
// Scan phase 1 (verified): per-chunk final state over bf16 Bu
// ---------------------------------------------------------------------------
__global__ __launch_bounds__(256) void scan_carry_kernel(
    const ushort2* __restrict__ Bu2, const float2* __restrict__ lam,
    float2* __restrict__ carry)
{
  const int n = threadIdx.x, b = blockIdx.x;
  const float2 la = lam[n];
  float sre = 0.f, sim = 0.f;
  const ushort2* p = Bu2 + (size_t)b * LC * NDIM + n;
#pragma unroll 8
  for (int j = 0; j < LC; ++j) {
    ushort2 bu = p[(size_t)j * NDIM];
    float bre = bf2f(bu.x), bim = bf2f(bu.y);
    float nre = la.x * sre - la.y * sim + bre;
    float nim = la.x * sim + la.y * sre + bim;
    sre = nre; sim = nim;
  }
  carry[(size_t)b * NDIM + n] = make_float2(sre, sim);
}

// ---------------------------------------------------------------------------
// Scan phase 2 (verified): log-depth Hillis-Steele in LDS.
// ---------------------------------------------------------------------------
__global__ __launch_bounds__(512) void carry_scan_kernel(
    const float2* __restrict__ carry, const float2* __restrict__ lam64,
    float2* __restrict__ corr)
{
  __shared__ float4 e[NCHUNK];
  const int n = blockIdx.x;
  const int b = threadIdx.x;
  float2 a = lam64[n];
  float2 v = carry[(size_t)b * NDIM + n];
  e[b] = make_float4(a.x, a.y, v.x, v.y);
  __syncthreads();
#pragma unroll
  for (int d = 1; d < NCHUNK; d <<= 1) {
    float4 prev;
    if (b >= d) prev = e[b - d];
    __syncthreads();
    if (b >= d) {
      float2 ap = make_float2(prev.x, prev.y), vp = make_float2(prev.z, prev.w);
      float2 na, nv;
      na.x = a.x * ap.x - a.y * ap.y;
      na.y = a.x * ap.y + a.y * ap.x;
      nv.x = a.x * vp.x - a.y * vp.y + v.x;
      nv.y = a.x * vp.y + a.y * vp.x + v.y;
      a = na; v = nv;
      e[b] = make_float4(a.x, a.y, v.x, v.y);
    }
    __syncthreads();
  }
  if (b == 0) corr[n] = make_float2(0.f, 0.f);
  if (b < NCHUNK - 1) corr[(size_t)(b + 1) * NDIM + n] = v;
}

// ---------------------------------------------------------------------------
// GEMM2 fused (R9-verified structure): one block = one chunk x 256 cols,
// 4 waves, 64x64 per wave. Ccat pre-swizzled -> bfr conflict-free via XOR.
// ---------------------------------------------------------------------------
__global__ __launch_bounds__(256, 2) void gemm2_kernel(
    const u16* __restrict__ Bu,   // L x 512 bf16
    const u16* __restrict__ Cc,   // 256 x 512 bf16 (pre-swizzled)
    const float2* __restrict__ lam,
    const float2* __restrict__ corr,
    const u16* __restrict__ xbf,  // L x 256 bf16
    const float* __restrict__ Dv,
    float* __restrict__ out)      // L x 256 f32
{
  constexpr int BM = 64, BK = 32, K = NCAT; // 16 k-steps
  __shared__ u16 sT[BM * K];      // 64KB: Bu tile -> (swizzled) s tile
  __shared__ u16 lB1[256 * BK];   // 16KB Ccat slice
  const int tid = threadIdx.x;
  const int lane = tid & 63, wave = tid >> 6;
  const int bm = blockIdx.x;
  const int row0 = bm * BM;
  const int wn = wave * 64;
  const int fr = lane & 15, fq = lane >> 4;
  char* sb = (char*)sT;
  const char* cbB = (const char*)lB1;

  // stage Bu tile linear (4096 x 16B) + Ccat slice kt=0 (1024 x 16B)
#pragma unroll
  for (int j = 0; j < 16; ++j) {
    int q = j * 256 + tid;
    int row = q >> 6, off = q & 63;
    const u16* g = Bu + (size_t)(row0 + row) * NCAT + off * 8;
    __builtin_amdgcn_global_load_lds((gbl_void*)g, (lds_void*)&sT[q * 8], 16, 0, 0);
  }
#pragma unroll
  for (int j = 0; j < 4; ++j) {
    int q = j * 256 + tid;
    int row = q >> 2, c = q & 3;
    const u16* g = Cc + (size_t)row * K + c * 8;
    __builtin_amdgcn_global_load_lds((gbl_void*)g, (lds_void*)&lB1[q * 8], 16, 0, 0);
  }
  float2 la = lam[tid];
  float2 c0 = corr[(size_t)bm * NDIM + tid];
  __syncthreads();

  // in-place scan (verified): read linear, write swizzled
  {
    float sre = c0.x, sim = c0.y;
    ushort2 buf[8], nbuf[8];
    const int lb = tid * 4;
#pragma unroll
    for (int s = 0; s < 8; ++s) buf[s] = *(const ushort2*)(sb + s * 1024 + lb);
#pragma unroll
    for (int b8 = 0; b8 < 8; ++b8) {
      if (b8 < 7) {
#pragma unroll
        for (int s = 0; s < 8; ++s)
          nbuf[s] = *(const ushort2*)(sb + (b8 * 8 + 8 + s) * 1024 + lb);
      }
#pragma unroll
      for (int s = 0; s < 8; ++s) {
        int row = b8 * 8 + s;
        float bre = bf2f(buf[s].x), bim = bf2f(buf[s].y);
        float nre = la.x * sre - la.y * sim + bre;
        float nim = la.x * sim + la.y * sre + bim;
        sre = nre; sim = nim;
        *(ushort2*)(sb + row * 1024 + (lb ^ ((row & 7) << 4))) =
            make_ushort2(f2bf(sre), f2bf(sim));
      }
#pragma unroll
      for (int s = 0; s < 8; ++s) buf[s] = nbuf[s];
    }
  }
  __syncthreads();

  // MFMA: 16 k-steps, reg-prefetch pipeline (R8/R9-verified)
  f32x4 acc[4][4] = {};
#pragma unroll 1
  for (int kt = 0; kt < 16; ++kt) {
    bf16x8 af[4], bfr[4];
#pragma unroll
    for (int j = 0; j < 4; ++j) {
      int rowb = wn + j * 16 + fr;
      bfr[j] = *(const bf16x8*)(cbB + ((rowb * 64 + fq * 16) ^ ((rowb & 7) << 4)));
    }
#pragma unroll
    for (int i = 0; i < 4; ++i) {
      int row = i * 16 + fr;
      int wb = kt * 64 + fq * 16;
      af[i] = *(const bf16x8*)(sb + row * 1024 + (wb ^ ((row & 7) << 4)));
    }
    __syncthreads();
    __builtin_amdgcn_sched_barrier(0);
    if (kt < 15) {
#pragma unroll
      for (int j = 0; j < 4; ++j) {
        int q = j * 256 + tid;
        int row = q >> 2, c = q & 3;
        const u16* g = Cc + (size_t)row * K + (kt + 1) * BK + c * 8;
        __builtin_amdgcn_global_load_lds((gbl_void*)g, (lds_void*)&lB1[q * 8], 16, 0, 0);
      }
    }
    __builtin_amdgcn_sched_barrier(0);
#pragma unroll
    for (int i = 0; i < 4; ++i)
#pragma unroll
      for (int j = 0; j < 4; ++j)
        acc[i][j] = __builtin_amdgcn_mfma_f32_16x16x32_bf16(af[i], bfr[j], acc[i][j], 0, 0, 0);
    __syncthreads();
  }

  // epilogue: y = acc + x*D
#pragma unroll
  for (int i = 0; i < 4; ++i)
#pragma unroll
    for (int j = 0; j < 4; ++j) {
      int cg = wn + j * 16 + fr;
      float dvc = Dv[cg];
#pragma unroll
      for (int r = 0; r < 4; ++r) {
        int rg = row0 + i * 16 + fq * 4 + r;
        float v = acc[i][j][r] + bf2f(xbf[(size_t)rg * HDIM + cg]) * dvc;
        out[(size_t)rg * HDIM + cg] = v;
      }
    }
}

// ---------------------------------------------------------------------------
extern "C" void kernel_launch(void* const* d_in, const int* in_sizes, int n_in,
                              void* d_out, int out_size, void* d_ws, size_t ws_size,
                              hipStream_t stream)
{
  (void)in_sizes; (void)n_in; (void)out_size; (void)ws_size;
  const float* x         = (const float*)d_in[0];
  const float* nu_log    = (const float*)d_in[1];
  const float* theta_log = (const float*)d_in[2];
  const float* B_re      = (const float*)d_in[3];
  const float* B_im      = (const float*)d_in[4];
  const float* C_re      = (const float*)d_in[5];
  const float* C_im      = (const float*)d_in[6];
  const float* Dv        = (const float*)d_in[7];
  const float* gamma_log = (const float*)d_in[8];

  char* ws = (char*)d_ws;
  u16*    x_bf  = (u16*)ws;                                  // 16 MB
  u16*    Bu_bf = (u16*)(ws + ((size_t)16 << 20));           // 32 MB
  u16*    Bcat  = (u16*)(ws + ((size_t)48 << 20));           // 256 KB
  u16*    Ccat  = (u16*)(ws + ((size_t)48 << 20) + 262144);  // 256 KB
  float2* lam   = (float2*)(ws + ((size_t)48 << 20) + 524288);
  float2* lam64 = (float2*)(ws + ((size_t)48 << 20) + 524288 + 4096);
  float2* carry = (float2*)(ws + ((size_t)49 << 20));        // 1 MB
  float2* corr  = (float2*)(ws + ((size_t)50 << 20));        // 1 MB

  prep_kernel<<<2817, 256, 0, stream>>>(x, nu_log, theta_log, B_re, B_im,
                                        C_re, C_im, gamma_log,
                                        x_bf, Bcat, Ccat, lam, lam64);

  gemm1_kernel<<<dim3(NCAT / 128, L_SEQ / 128), 256, 0, stream>>>(
      x_bf, Bcat, Bu_bf, L_SEQ, NCAT, HDIM);

  scan_carry_kernel<<<NCHUNK, 256, 0, stream>>>((const ushort2*)Bu_bf, lam, carry);

  carry_scan_kernel<<<NDIM, 512, 0, stream>>>(carry, lam64, corr);

  gemm2_kernel<<<NCHUNK, 256, 0, stream>>>(
      Bu_bf, Ccat, lam, corr, x_bf, Dv, (float*)d_out);
}

// Round 11
// 72.511 us; speedup vs baseline: 1.0175x; 1.0173x over previous
//
#include <hip/hip_runtime.h>

#define L_SEQ 32768
#define NDIM 256
#define HDIM 256
#define NCAT 512   // 2*NDIM (re/im interleaved)
#define LC 64      // scan chunk length
#define NCHUNK 512 // L_SEQ / LC

typedef unsigned short u16;
typedef unsigned int u32;
typedef __bf16 bf16x8 __attribute__((ext_vector_type(8)));
typedef float f32x4 __attribute__((ext_vector_type(4)));
typedef __attribute__((address_space(3))) void lds_void;
typedef const __attribute__((address_space(1))) void gbl_void;

__device__ __forceinline__ u16 f2bf(float f) {
  u32 u = __builtin_bit_cast(u32, f);
  u = u + 0x7fffu + ((u >> 16) & 1u);
  return (u16)(u >> 16);
}
__device__ __forceinline__ float bf2f(u16 v) {
  u32 u = ((u32)v) << 16;
  return __builtin_bit_cast(float, u);
}

// ---------------------------------------------------------------------------
// PREP: x -> bf16 (PRE-SWIZZLED: within each 64-el k-segment, 8-el block
// b ^= row&7 -> x_bf[r][c ^ ((r&7)<<3)] = x[r][c]); Bcat same recipe;
// Ccat pre-swizzled for gemm2's BK=32 read (R10 geometry, verified); lambdas.
// ---------------------------------------------------------------------------
__global__ __launch_bounds__(256) void prep_kernel(
    const float* __restrict__ x,
    const float* __restrict__ nu_log, const float* __restrict__ theta_log,
    const float* __restrict__ B_re, const float* __restrict__ B_im,
    const float* __restrict__ C_re, const float* __restrict__ C_im,
    const float* __restrict__ gamma_log,
    u16* __restrict__ x_bf, u16* __restrict__ Bcat, u16* __restrict__ Ccat,
    float2* __restrict__ lam, float2* __restrict__ lam64)
{
  const int blk = blockIdx.x, tid = threadIdx.x;
  if (blk < 2048) {
    const float4* src = (const float4*)x;
#pragma unroll
    for (int j = 0; j < 4; ++j) {
      int i = blk * 1024 + j * 256 + tid;
      int r = i >> 6;
      int col = (i & 63) * 4;
      float4 v = src[i];
      int pcol = col ^ ((r & 7) << 3);
      *(ushort4*)(x_bf + (size_t)r * 256 + pcol) =
          make_ushort4(f2bf(v.x), f2bf(v.y), f2bf(v.z), f2bf(v.w));
    }
  } else if (blk < 2560) {
    // Bcat row pr: even = B_re*g, odd = B_im*g; cols block-permuted by pr&7
    int pr = blk - 2048;
    int jj = pr >> 1, p = pr & 1;
    float g = expf(gamma_log[jj]);
    const float* src = (p ? B_im : B_re) + (size_t)jj * HDIM;
    int lc = tid ^ ((pr & 7) << 3);
    Bcat[(size_t)pr * HDIM + tid] = f2bf(src[lc] * g);
  } else if (blk < 2816) {
    // Ccat (R10-verified builder for gemm2's BK=32 swizzled read):
    // physical row ph holds logical row lr = ph^((ph>>2)&1), cols permuted
    int ph = blk - 2560;
    int lr = ph ^ ((ph >> 2) & 1);
#pragma unroll
    for (int half = 0; half < 2; ++half) {
      int pcol = half * 256 + tid;
      int kt = pcol >> 5, w = pcol & 31, pc = w >> 3, e = w & 7;
      int lc2 = kt * 32 + (pc ^ (lr & 3)) * 8 + e;
      int jj = lc2 >> 1, p = lc2 & 1;
      float v = p ? -C_im[(size_t)lr * NDIM + jj] : C_re[(size_t)lr * NDIM + jj];
      Ccat[(size_t)ph * NCAT + pcol] = f2bf(v);
    }
  } else {
    float nu_e = expf(nu_log[tid]);
    float th = expf(theta_log[tid]);
    float r = expf(-nu_e);
    lam[tid] = make_float2(r * cosf(th), r * sinf(th));
    float r64 = expf(-(float)LC * nu_e);
    float ph = (float)LC * th;
    lam64[tid] = make_float2(r64 * cosf(ph), r64 * sinf(ph));
  }
}

// ---------------------------------------------------------------------------
// GEMM1: Bu[m][n] = sum_k A[m][k]*Bm[n][k], bf16 out. BK=64: 4 k-stages of
// 32 MFMA (halves the stage->drain barrier count vs BK=32). Both operands
// pre-swizzled in global memory -> conflict-floor XOR reads (rule #21).
// Same k-summation order as BK=32 version -> bit-identical output.
// ---------------------------------------------------------------------------
__global__ __launch_bounds__(256) void gemm1_kernel(
    const u16* __restrict__ A,   // M x K bf16 (cols pre-swizzled per row)
    const u16* __restrict__ Bm,  // N x K bf16 (cols pre-swizzled per row)
    u16* __restrict__ Cout,      // M x N bf16
    int M, int N, int K)
{
  constexpr int BM = 128, BN = 128, BK = 64;
  __shared__ u16 lA[BM * BK];   // 16KB
  __shared__ u16 lB[BN * BK];   // 16KB
  const int tid = threadIdx.x;
  const int lane = tid & 63, wave = tid >> 6;
  const int bn = blockIdx.x, bm = blockIdx.y;
  const int row0 = bm * BM, col0 = bn * BN;
  const int wm = (wave >> 1) * 64, wn = (wave & 1) * 64;
  const int fr = lane & 15, fq = lane >> 4;
  const int swz = (fr & 7) << 4;
  const char* lab = (const char*)lA;
  const char* lbb = (const char*)lB;

  f32x4 acc[4][4] = {};
  const int nkt = K / BK;  // 4
  for (int kt = 0; kt < nkt; ++kt) {
    const int k0 = kt * BK;
#pragma unroll
    for (int j = 0; j < 4; ++j) {
      int c = j * 256 + tid;          // 1024 x 16B chunks per matrix
      int r = c >> 3, b = c & 7;
      const u16* ga = A + (size_t)(row0 + r) * K + (k0 + b * 8);
      const u16* gb = Bm + (size_t)(col0 + r) * K + (k0 + b * 8);
      __builtin_amdgcn_global_load_lds((gbl_void*)ga, (lds_void*)&lA[c * 8], 16, 0, 0);
      __builtin_amdgcn_global_load_lds((gbl_void*)gb, (lds_void*)&lB[c * 8], 16, 0, 0);
    }
    __syncthreads();

#pragma unroll
    for (int h = 0; h < 2; ++h) {
      bf16x8 af[4], bfr[4];
      const int ko = (h * 64 + fq * 16) ^ swz;
#pragma unroll
      for (int i = 0; i < 4; ++i) {
        af[i]  = *(const bf16x8*)(lab + (wm + i * 16 + fr) * 128 + ko);
        bfr[i] = *(const bf16x8*)(lbb + (wn + i * 16 + fr) * 128 + ko);
      }
#pragma unroll
      for (int i = 0; i < 4; ++i)
#pragma unroll
        for (int j = 0; j < 4; ++j)
          acc[i][j] = __builtin_amdgcn_mfma_f32_16x16x32_bf16(af[i], bfr[j], acc[i][j], 0, 0, 0);
    }
    __syncthreads();
  }

  const int fq2 = lane >> 4;
#pragma unroll
  for (int i = 0; i < 4; ++i)
#pragma unroll
    for (int j = 0; j < 4; ++j) {
      int cg = col0 + wn + j * 16 + fr;
#pragma unroll
      for (int r = 0; r < 4; ++r) {
        int rg = row0 + wm + i * 16 + fq2 * 4 + r;
        Cout[(size_t)rg * N + cg] = f2bf(acc[i][j][r]);
      }
    }
}

// ---------------------------------------------------------------------------
// Scan phase 1 (verified): per-chunk final state over bf16 Bu
// ---------------------------------------------------------------------------
__global__ __launch_bounds__(256) void scan_carry_kernel(
    const ushort2* __restrict__ Bu2, const float2* __restrict__ lam,
    float2* __restrict__ carry)
{
  const int n = threadIdx.x, b = blockIdx.x;
  const float2 la = lam[n];
  float sre = 0.f, sim = 0.f;
  const ushort2* p = Bu2 + (size_t)b * LC * NDIM + n;
#pragma unroll 8
  for (int j = 0; j < LC; ++j) {
    ushort2 bu = p[(size_t)j * NDIM];
    float bre = bf2f(bu.x), bim = bf2f(bu.y);
    float nre = la.x * sre - la.y * sim + bre;
    float nim = la.x * sim + la.y * sre + bim;
    sre = nre; sim = nim;
  }
  carry[(size_t)b * NDIM + n] = make_float2(sre, sim);
}

// ---------------------------------------------------------------------------
// Scan phase 2 (verified): log-depth Hillis-Steele in LDS.
// ---------------------------------------------------------------------------
__global__ __launch_bounds__(512) void carry_scan_kernel(
    const float2* __restrict__ carry, const float2* __restrict__ lam64,
    float2* __restrict__ corr)
{
  __shared__ float4 e[NCHUNK];
  const int n = blockIdx.x;
  const int b = threadIdx.x;
  float2 a = lam64[n];
  float2 v = carry[(size_t)b * NDIM + n];
  e[b] = make_float4(a.x, a.y, v.x, v.y);
  __syncthreads();
#pragma unroll
  for (int d = 1; d < NCHUNK; d <<= 1) {
    float4 prev;
    if (b >= d) prev = e[b - d];
    __syncthreads();
    if (b >= d) {
      float2 ap = make_float2(prev.x, prev.y), vp = make_float2(prev.z, prev.w);
      float2 na, nv;
      na.x = a.x * ap.x - a.y * ap.y;
      na.y = a.x * ap.y + a.y * ap.x;
      nv.x = a.x * vp.x - a.y * vp.y + v.x;
      nv.y = a.x * vp.y + a.y * vp.x + v.y;
      a = na; v = nv;
      e[b] = make_float4(a.x, a.y, v.x, v.y);
    }
    __syncthreads();
  }
  if (b == 0) corr[n] = make_float2(0.f, 0.f);
  if (b < NCHUNK - 1) corr[(size_t)(b + 1) * NDIM + n] = v;
}

// ---------------------------------------------------------------------------
// GEMM2 fused (R10-verified, unchanged except epilogue xbf swizzle index):
// one block = one chunk x 256 cols, 4 waves, 64x64 per wave.
// ---------------------------------------------------------------------------
__global__ __launch_bounds__(256, 2) void gemm2_kernel(
    const u16* __restrict__ Bu,   // L x 512 bf16
    const u16* __restrict__ Cc,   // 256 x 512 bf16 (pre-swizzled)
    const float2* __restrict__ lam,
    const float2* __restrict__ corr,
    const u16* __restrict__ xbf,  // L x 256 bf16 (pre-swizzled cols)
    const float* __restrict__ Dv,
    float* __restrict__ out)      // L x 256 f32
{
  constexpr int BM = 64, BK = 32, K = NCAT; // 16 k-steps
  __shared__ u16 sT[BM * K];      // 64KB: Bu tile -> (swizzled) s tile
  __shared__ u16 lB1[256 * BK];   // 16KB Ccat slice
  const int tid = threadIdx.x;
  const int lane = tid & 63, wave = tid >> 6;
  const int bm = blockIdx.x;
  const int row0 = bm * BM;
  const int wn = wave * 64;
  const int fr = lane & 15, fq = lane >> 4;
  char* sb = (char*)sT;
  const char* cbB = (const char*)lB1;

  // stage Bu tile linear (4096 x 16B) + Ccat slice kt=0 (1024 x 16B)
#pragma unroll
  for (int j = 0; j < 16; ++j) {
    int q = j * 256 + tid;
    int row = q >> 6, off = q & 63;
    const u16* g = Bu + (size_t)(row0 + row) * NCAT + off * 8;
    __builtin_amdgcn_global_load_lds((gbl_void*)g, (lds_void*)&sT[q * 8], 16, 0, 0);
  }
#pragma unroll
  for (int j = 0; j < 4; ++j) {
    int q = j * 256 + tid;
    int row = q >> 2, c = q & 3;
    const u16* g = Cc + (size_t)row * K + c * 8;
    __builtin_amdgcn_global_load_lds((gbl_void*)g, (lds_void*)&lB1[q * 8], 16, 0, 0);
  }
  float2 la = lam[tid];
  float2 c0 = corr[(size_t)bm * NDIM + tid];
  __syncthreads();

  // in-place scan (verified): read linear, write swizzled
  {
    float sre = c0.x, sim = c0.y;
    ushort2 buf[8], nbuf[8];
    const int lb = tid * 4;
#pragma unroll
    for (int s = 0; s < 8; ++s) buf[s] = *(const ushort2*)(sb + s * 1024 + lb);
#pragma unroll
    for (int b8 = 0; b8 < 8; ++b8) {
      if (b8 < 7) {
#pragma unroll
        for (int s = 0; s < 8; ++s)
          nbuf[s] = *(const ushort2*)(sb + (b8 * 8 + 8 + s) * 1024 + lb);
      }
#pragma unroll
      for (int s = 0; s < 8; ++s) {
        int row = b8 * 8 + s;
        float bre = bf2f(buf[s].x), bim = bf2f(buf[s].y);
        float nre = la.x * sre - la.y * sim + bre;
        float nim = la.x * sim + la.y * sre + bim;
        sre = nre; sim = nim;
        *(ushort2*)(sb + row * 1024 + (lb ^ ((row & 7) << 4))) =
            make_ushort2(f2bf(sre), f2bf(sim));
      }
#pragma unroll
      for (int s = 0; s < 8; ++s) buf[s] = nbuf[s];
    }
  }
  __syncthreads();

  // MFMA: 16 k-steps, reg-prefetch pipeline (R8/R9/R10-verified)
  f32x4 acc[4][4] = {};
#pragma unroll 1
  for (int kt = 0; kt < 16; ++kt) {
    bf16x8 af[4], bfr[4];
#pragma unroll
    for (int j = 0; j < 4; ++j) {
      int rowb = wn + j * 16 + fr;
      bfr[j] = *(const bf16x8*)(cbB + ((rowb * 64 + fq * 16) ^ ((rowb & 7) << 4)));
    }
#pragma unroll
    for (int i = 0; i < 4; ++i) {
      int row = i * 16 + fr;
      int wb = kt * 64 + fq * 16;
      af[i] = *(const bf16x8*)(sb + row * 1024 + (wb ^ ((row & 7) << 4)));
    }
    __syncthreads();
    __builtin_amdgcn_sched_barrier(0);
    if (kt < 15) {
#pragma unroll
      for (int j = 0; j < 4; ++j) {
        int q = j * 256 + tid;
        int row = q >> 2, c = q & 3;
        const u16* g = Cc + (size_t)row * K + (kt + 1) * BK + c * 8;
        __builtin_amdgcn_global_load_lds((gbl_void*)g, (lds_void*)&lB1[q * 8], 16, 0, 0);
      }
    }
    __builtin_amdgcn_sched_barrier(0);
#pragma unroll
    for (int i = 0; i < 4; ++i)
#pragma unroll
      for (int j = 0; j < 4; ++j)
        acc[i][j] = __builtin_amdgcn_mfma_f32_16x16x32_bf16(af[i], bfr[j], acc[i][j], 0, 0, 0);
    __syncthreads();
  }

  // epilogue: y = acc + x*D (xbf cols pre-swizzled: c -> c ^ ((r&7)<<3))
#pragma unroll
  for (int i = 0; i < 4; ++i)
#pragma unroll
    for (int j = 0; j < 4; ++j) {
      int cg = wn + j * 16 + fr;
      float dvc = Dv[cg];
#pragma unroll
      for (int r = 0; r < 4; ++r) {
        int rg = row0 + i * 16 + fq * 4 + r;
        float v = acc[i][j][r] +
                  bf2f(xbf[(size_t)rg * HDIM + (cg ^ ((rg & 7) << 3))]) * dvc;
        out[(size_t)rg * HDIM + cg] = v;
      }
    }
}

// ---------------------------------------------------------------------------
extern "C" void kernel_launch(void* const* d_in, const int* in_sizes, int n_in,
                              void* d_out, int out_size, void* d_ws, size_t ws_size,
                              hipStream_t stream)
{
  (void)in_sizes; (void)n_in; (void)out_size; (void)ws_size;
  const float* x         = (const float*)d_in[0];
  const float* nu_log    = (const float*)d_in[1];
  const float* theta_log = (const float*)d_in[2];
  const float* B_re      = (const float*)d_in[3];
  const float* B_im      = (const float*)d_in[4];
  const float* C_re      = (const float*)d_in[5];
  const float* C_im      = (const float*)d_in[6];
  const float* Dv        = (const float*)d_in[7];
  const float* gamma_log = (const float*)d_in[8];

  char* ws = (char*)d_ws;
  u16*    x_bf  = (u16*)ws;                                  // 16 MB
  u16*    Bu_bf = (u16*)(ws + ((size_t)16 << 20));           // 32 MB
  u16*    Bcat  = (u16*)(ws + ((size_t)48 << 20));           // 256 KB
  u16*    Ccat  = (u16*)(ws + ((size_t)48 << 20) + 262144);  // 256 KB
  float2* lam   = (float2*)(ws + ((size_t)48 << 20) + 524288);
  float2* lam64 = (float2*)(ws + ((size_t)48 << 20) + 524288 + 4096);
  float2* carry = (float2*)(ws + ((size_t)49 << 20));        // 1 MB
  float2* corr  = (float2*)(ws + ((size_t)50 << 20));        // 1 MB

  prep_kernel<<<2817, 256, 0, stream>>>(x, nu_log, theta_log, B_re, B_im,
                                        C_re, C_im, gamma_log,
                                        x_bf, Bcat, Ccat, lam, lam64);

  gemm1_kernel<<<dim3(NCAT / 128, L_SEQ / 128), 256, 0, stream>>>(
      x_bf, Bcat, Bu_bf, L_SEQ, NCAT, HDIM);

  scan_carry_kernel<<<NCHUNK, 256, 0, stream>>>((const ushort2*)Bu_bf, lam, carry);

  carry_scan_kernel<<<NDIM, 512, 0, stream>>>(carry, lam64, corr);

  gemm2_kernel<<<NCHUNK, 256, 0, stream>>>(
      Bu_bf, Ccat, lam, corr, x_bf, Dv, (float*)d_out);
}